// Round 5
// baseline (4048.284 us; speedup 1.0000x reference)
//
#include <hip/hip_runtime.h>
#include <hip/hip_bf16.h>
#include <cstddef>
#include <cstdint>

// ---------------------------------------------------------------------------
// DeBERTa forward, MI355X. Round 5: flash_attn v2 (LDS-traffic-halved:
// reg-Q, shared K-frags, column-split band GEMMs, T14 prefetch, setprio).
// B=8 S=512 HID=768 L=12 NH=12 D=64 FF=3072 2M=1024
// ---------------------------------------------------------------------------

constexpr int B   = 8;
constexpr int S   = 512;
constexpr int HID = 768;
constexpr int L   = 12;
constexpr int NH  = 12;
constexpr int D   = 64;
constexpr int FF  = 3072;
constexpr int M2  = 1024;          // 2*M
constexpr int NTOK = B * S;        // 4096

using f32x4 = __attribute__((ext_vector_type(4))) float;
using s16x8 = __attribute__((ext_vector_type(8))) short;

__device__ inline float wave_sum(float v) {
#pragma unroll
  for (int o = 32; o > 0; o >>= 1) v += __shfl_xor(v, o, 64);
  return v;
}
__device__ inline unsigned short f2bf(float f) {
  __hip_bfloat16 h = __float2bfloat16(f);
  return *reinterpret_cast<unsigned short*>(&h);
}
__device__ inline float bf2f(unsigned short u) {
  union { unsigned int i; float f; } x;
  x.i = ((unsigned int)u) << 16;
  return x.f;
}
#define GLOAD16(gp, lp)                                                  \
  __builtin_amdgcn_global_load_lds(                                     \
      (const __attribute__((address_space(1))) void*)(gp),              \
      (__attribute__((address_space(3))) void*)(lp), 16, 0, 0)

// ---- embeddings -------------------------------------------------------------
__global__ void embed_kernel(const int* __restrict__ tok,
                             const int* __restrict__ seg,
                             const float* __restrict__ tok_emb,
                             const float* __restrict__ seg_emb,
                             float* __restrict__ x) {
  int row = blockIdx.x;
  int s = row & (S - 1);
  int t = tok[row];
  int sg = seg[row];
  for (int c = threadIdx.x; c < HID; c += blockDim.x) {
    int i = c >> 1;
    float ang = (float)s * powf(10000.0f, -2.0f * (float)i / (float)HID);
    float pe = (c & 1) ? cosf(ang) : sinf(ang);
    x[(size_t)row * HID + c] = tok_emb[(size_t)t * HID + c] + pe
                             + seg_emb[(size_t)sg * HID + c];
  }
}

// ---- layernorm (one wave per row) -------------------------------------------
template <int BF16OUT>
__global__ __launch_bounds__(256)
void ln_kernel(const float* __restrict__ in, void* __restrict__ outp,
               const float* __restrict__ g, const float* __restrict__ b,
               int nrows) {
  int wave = threadIdx.x >> 6, lane = threadIdx.x & 63;
  int row = blockIdx.x * 4 + wave;
  if (row >= nrows) return;
  const float* xr = in + (size_t)row * HID;
  float v[12];
  float s = 0.f;
#pragma unroll
  for (int i = 0; i < 12; i++) { v[i] = xr[lane + i * 64]; s += v[i]; }
  s = wave_sum(s);
  float mu = s * (1.0f / HID);
  float ss = 0.f;
#pragma unroll
  for (int i = 0; i < 12; i++) { float d = v[i] - mu; ss += d * d; }
  ss = wave_sum(ss);
  float inv = rsqrtf(ss * (1.0f / HID) + 1e-5f);
#pragma unroll
  for (int i = 0; i < 12; i++) {
    int c = lane + i * 64;
    float o = (v[i] - mu) * inv * g[c] + b[c];
    if (BF16OUT)
      ((unsigned short*)outp)[(size_t)row * HID + c] = f2bf(o);
    else
      ((float*)outp)[(size_t)row * HID + c] = o;
  }
}

// ---- 6 square [HID,HID] weights transpose+bf16 in one dispatch ---------------
__global__ __launch_bounds__(256)
void transpose6_kernel(const float* s0, const float* s1, const float* s2,
                       const float* s3, const float* s4, const float* s5,
                       unsigned short* __restrict__ dst) {
  const float* srcs[6] = {s0, s1, s2, s3, s4, s5};
  const float* src = srcs[blockIdx.z];
  unsigned short* d = dst + (size_t)blockIdx.z * HID * HID;
  __shared__ float tile[32][33];
  int nt = blockIdx.x * 32, kt = blockIdx.y * 32;
  int tx = threadIdx.x & 31, ty = threadIdx.x >> 5;
#pragma unroll
  for (int i = 0; i < 4; i++)
    tile[ty + i * 8][tx] = src[(size_t)(kt + ty + i * 8) * HID + nt + tx];
  __syncthreads();
#pragma unroll
  for (int i = 0; i < 4; i++)
    d[(size_t)(nt + ty + i * 8) * HID + kt + tx] = f2bf(tile[tx][ty + i * 8]);
}

// ---- W1+W2 transpose+bf16 in one dispatch (z=0:W1, z=1:W2) -------------------
__global__ __launch_bounds__(256)
void transpose_ff(const float* __restrict__ W1s, const float* __restrict__ W2s,
                  unsigned short* __restrict__ d1, unsigned short* __restrict__ d2) {
  const float* src = blockIdx.z ? W2s : W1s;
  unsigned short* dst = blockIdx.z ? d2 : d1;
  int K = blockIdx.z ? FF : HID;   // src rows
  int N = blockIdx.z ? HID : FF;   // src cols
  int nt, kt;
  if (blockIdx.z) { nt = blockIdx.y * 32; kt = blockIdx.x * 32; }
  else            { nt = blockIdx.x * 32; kt = blockIdx.y * 32; }
  __shared__ float tile[32][33];
  int tx = threadIdx.x & 31, ty = threadIdx.x >> 5;
#pragma unroll
  for (int i = 0; i < 4; i++)
    tile[ty + i * 8][tx] = src[(size_t)(kt + ty + i * 8) * N + nt + tx];
  __syncthreads();
#pragma unroll
  for (int i = 0; i < 4; i++)
    dst[(size_t)(nt + ty + i * 8) * K + kt + tx] = f2bf(tile[tx][ty + i * 8]);
}

__global__ void conv_bf16_kernel(const float* __restrict__ src,
                                 unsigned short* __restrict__ dst, int n) {
  int i = blockIdx.x * 256 + threadIdx.x;
  if (i < n) dst[i] = f2bf(src[i]);
}

__global__ void concat_bias(const float* __restrict__ bq,
                            const float* __restrict__ bk,
                            const float* __restrict__ bv,
                            float* __restrict__ bqkv) {
  int i = blockIdx.x * 256 + threadIdx.x;
  if (i >= L * 2304) return;
  int l = i / 2304, c = i % 2304;
  float v = (c < 768) ? bq[l * 768 + c]
          : (c < 1536) ? bk[l * 768 + c - 768] : bv[l * 768 + c - 1536];
  bqkv[i] = v;
}

// ---- bf16 MFMA GEMM, 128xTN tile, optional split-K partial ------------------
template <int TN, int OUT_BF16, int GELU, int PARTIAL>
__global__ __launch_bounds__(256)
void mfma_gemm(const unsigned short* __restrict__ A,
               const unsigned short* __restrict__ Bt,
               const float* __restrict__ bias, const float* __restrict__ res,
               void* __restrict__ C, int Mr, int K, int N, int Kc) {
  constexpr int NW = TN / 32;
  __shared__ unsigned short As[128 * 32];
  __shared__ unsigned short Bs[TN * 32];
  int t = threadIdx.x, wave = t >> 6, lane = t & 63;
  int r0 = blockIdx.y * 128, n0 = blockIdx.x * TN;
  int kb = blockIdx.z * Kc;
  int wr = (wave >> 1) * 64;
  int wc = (wave & 1) * (TN / 2);

  f32x4 acc[4][NW] = {};
  int srow = lane >> 2, selem = (lane & 3) * 8;

  for (int k0 = kb; k0 < kb + Kc; k0 += 32) {
    __syncthreads();
    {
      const unsigned short* gA =
          A + (size_t)(r0 + wave * 32 + srow) * K + k0 + selem;
      unsigned short* lA = &As[(wave * 32) * 32];
      GLOAD16(gA, lA);
      GLOAD16(gA + (size_t)16 * K, lA + 16 * 32);
      if (TN == 128) {
        const unsigned short* gB =
            Bt + (size_t)(n0 + wave * 32 + srow) * K + k0 + selem;
        unsigned short* lB = &Bs[(wave * 32) * 32];
        GLOAD16(gB, lB);
        GLOAD16(gB + (size_t)16 * K, lB + 16 * 32);
      } else {
        const unsigned short* gB =
            Bt + (size_t)(n0 + wave * 16 + srow) * K + k0 + selem;
        GLOAD16(gB, &Bs[(wave * 16) * 32]);
      }
    }
    __syncthreads();

    s16x8 af[4], bf[NW];
#pragma unroll
    for (int m = 0; m < 4; m++)
      af[m] = *(const s16x8*)&As[(wr + m * 16 + (lane & 15)) * 32 + (lane >> 4) * 8];
#pragma unroll
    for (int n = 0; n < NW; n++)
      bf[n] = *(const s16x8*)&Bs[(wc + n * 16 + (lane & 15)) * 32 + (lane >> 4) * 8];
#pragma unroll
    for (int m = 0; m < 4; m++)
#pragma unroll
      for (int n = 0; n < NW; n++)
        acc[m][n] = __builtin_amdgcn_mfma_f32_16x16x32_bf16(af[m], bf[n],
                                                            acc[m][n], 0, 0, 0);
  }

  if (PARTIAL) {
    float* Cp = (float*)C + (size_t)blockIdx.z * Mr * N;
#pragma unroll
    for (int n = 0; n < NW; n++) {
      int c = n0 + wc + n * 16 + (lane & 15);
#pragma unroll
      for (int m = 0; m < 4; m++) {
        int rb = r0 + wr + m * 16 + ((lane >> 4) << 2);
#pragma unroll
        for (int j = 0; j < 4; j++)
          Cp[(size_t)(rb + j) * N + c] = acc[m][n][j];
      }
    }
    return;
  }
#pragma unroll
  for (int n = 0; n < NW; n++) {
    int c = n0 + wc + n * 16 + (lane & 15);
    float bv = bias ? bias[c] : 0.f;
#pragma unroll
    for (int m = 0; m < 4; m++) {
      int rb = r0 + wr + m * 16 + ((lane >> 4) << 2);
#pragma unroll
      for (int j = 0; j < 4; j++) {
        int r = rb + j;
        float val = acc[m][n][j] + bv;
        if (GELU) val = 0.5f * val * (1.0f + erff(val * 0.70710678118654752f));
        if (res)  val += res[(size_t)r * N + c];
        if (OUT_BF16)
          ((unsigned short*)C)[(size_t)r * N + c] = f2bf(val);
        else
          ((float*)C)[(size_t)r * N + c] = val;
      }
    }
  }
}

// ---- split-K combine + residual + LN ----------------------------------------
template <int LAST>
__global__ __launch_bounds__(256)
void combine_ln(const float* __restrict__ part,   // [2][NTOK][HID]
                float* __restrict__ x, const float* __restrict__ bias,
                const float* __restrict__ g, const float* __restrict__ bb,
                void* __restrict__ outp) {
  int row = blockIdx.x, t = threadIdx.x;
  int wave = t >> 6, lane = t & 63;
  __shared__ float red[4];
  float v[3];
  float s = 0.f;
#pragma unroll
  for (int i = 0; i < 3; i++) {
    int c = t + i * 256;
    size_t idx = (size_t)row * HID + c;
    float val = x[idx] + part[idx] + part[(size_t)NTOK * HID + idx] + bias[c];
    if (!LAST) x[idx] = val;
    v[i] = val;
    s += val;
  }
  s = wave_sum(s);
  if (lane == 0) red[wave] = s;
  __syncthreads();
  float mu = (red[0] + red[1] + red[2] + red[3]) * (1.0f / HID);
  float ss = 0.f;
#pragma unroll
  for (int i = 0; i < 3; i++) { float d = v[i] - mu; ss += d * d; }
  ss = wave_sum(ss);
  __syncthreads();
  if (lane == 0) red[wave] = ss;
  __syncthreads();
  float inv = rsqrtf((red[0] + red[1] + red[2] + red[3]) * (1.0f / HID) + 1e-5f);
#pragma unroll
  for (int i = 0; i < 3; i++) {
    int c = t + i * 256;
    float o = (v[i] - mu) * inv * g[c] + bb[c];
    if (LAST)
      ((float*)outp)[(size_t)row * HID + c] = o;
    else
      ((unsigned short*)outp)[(size_t)row * HID + c] = f2bf(o);
  }
}

// ---- V transpose from fused qkv ----------------------------------------------
__global__ __launch_bounds__(256)
void transpose_v(const unsigned short* __restrict__ qkv,
                 unsigned short* __restrict__ vt) {
  __shared__ unsigned short tile[32][34];
  int bh = blockIdx.z;
  int b = bh / NH, h = bh % NH;
  int s0 = blockIdx.x * 32, d0 = blockIdx.y * 32;
  int tx = threadIdx.x & 31, ty = threadIdx.x >> 5;
#pragma unroll
  for (int i = 0; i < 4; i++)
    tile[ty + i * 8][tx] =
        qkv[(size_t)(b * S + s0 + ty + i * 8) * 2304 + 1536 + h * 64 + d0 + tx];
  __syncthreads();
#pragma unroll
  for (int i = 0; i < 4; i++)
    vt[((size_t)bh * 64 + d0 + ty + i * 8) * S + s0 + tx] = tile[tx][ty + i * 8];
}

// ---- flash attention v2 ------------------------------------------------------
// 4 waves, 64 q-rows/block, 8 k-tiles. Q-frags in regs (loop-invariant).
// Per k-tile: c2c (row-split), cp/pc band GEMMs (column-split, shared K-frags),
// gather+online-softmax, PV. Next tile prefetched into regs (T14).
__global__ __launch_bounds__(256)
void flash_attn(const unsigned short* __restrict__ qkv,
                const unsigned short* __restrict__ pkq,  // [1024][1536] pk|pq
                const unsigned short* __restrict__ vt,   // [B*NH*64][S]
                const int* __restrict__ tok,
                unsigned short* __restrict__ ctx) {
  constexpr int RS = 72, TS = 130;
  __shared__ unsigned short KPs[64 * RS];       // K tile; aliased to P
  __shared__ unsigned short Vs[64 * RS];        // V^T tile [d][k]
  __shared__ unsigned short Band[2 * 128 * RS]; // PKb|PQb; aliased c2pL|p2cL
  __shared__ int smTok[64];
  unsigned short* PKb = Band;
  unsigned short* PQb = Band + 128 * RS;
  unsigned short* c2pL = Band;                  // [64][TS]
  unsigned short* p2cL = Band + 128 * RS;       // [64][TS]

  int t = threadIdx.x, wave = t >> 6, lane = t & 63;
  int bh = blockIdx.y;
  int b = bh / NH, h = bh % NH;
  int q0 = blockIdx.x * 64;
  int l15 = lane & 15, l4 = lane >> 4;
  const float scale = 0.07216878364870323f;    // 1/sqrt(3*64)

  // staging coords (per thread): two chunks for K/V, four for each band
  int sr0 = t >> 3, sd0 = (t & 7) * 8;         // chunk0: rows 0..31
  int sr1 = sr0 + 32;                          // chunk1: rows 32..63

  // ---- persistent Q fragments straight from global ----
  s16x8 qf[4][2];
#pragma unroll
  for (int m = 0; m < 4; m++)
#pragma unroll
    for (int ks = 0; ks < 2; ks++)
      qf[m][ks] = *(const s16x8*)&qkv[(size_t)(b * S + q0 + m * 16 + l15) * 2304
                                      + h * 64 + ks * 32 + l4 * 8];

  float mrow[4], lrow[4];
  f32x4 accO[4];
#pragma unroll
  for (int j = 0; j < 4; j++) { mrow[j] = -1e30f; lrow[j] = 0.f; }
#pragma unroll
  for (int n = 0; n < 4; n++) accO[n] = (f32x4){0.f, 0.f, 0.f, 0.f};

  // ---- prologue: stage tile 0 directly ----
  {
    *(s16x8*)&KPs[sr0 * RS + sd0] =
        *(const s16x8*)&qkv[(size_t)(b * S + sr0) * 2304 + 768 + h * 64 + sd0];
    *(s16x8*)&KPs[sr1 * RS + sd0] =
        *(const s16x8*)&qkv[(size_t)(b * S + sr1) * 2304 + 768 + h * 64 + sd0];
    *(s16x8*)&Vs[sr0 * RS + sd0] =
        *(const s16x8*)&vt[((size_t)bh * 64 + sr0) * S + sd0];
    *(s16x8*)&Vs[sr1 * RS + sd0] =
        *(const s16x8*)&vt[((size_t)bh * 64 + sr1) * S + sd0];
    int lo1 = q0 + 449, lo2 = -q0 + 449;
#pragma unroll
    for (int i = 0; i < 4; i++) {
      int tt = sr0 + i * 32;
      int r1 = lo1 + tt; r1 = r1 < 0 ? 0 : (r1 > M2 - 1 ? M2 - 1 : r1);
      int r2 = lo2 + tt; r2 = r2 < 0 ? 0 : (r2 > M2 - 1 ? M2 - 1 : r2);
      *(s16x8*)&PKb[tt * RS + sd0] =
          *(const s16x8*)&pkq[(size_t)r1 * 1536 + h * 64 + sd0];
      *(s16x8*)&PQb[tt * RS + sd0] =
          *(const s16x8*)&pkq[(size_t)r2 * 1536 + 768 + h * 64 + sd0];
    }
    if (t < 64) smTok[t] = tok[b * S + t];
  }
  __syncthreads();

  for (int k0 = 0; k0 < S; k0 += 64) {
    int k0n = k0 + 64;
    bool pfv = (k0n < S);

    // ---- T14: issue next tile's global loads into regs ----
    s16x8 pfK0, pfK1, pfV0, pfV1, pfPK[4], pfPQ[4];
    int pfTok = 0;
    if (pfv) {
      pfK0 = *(const s16x8*)&qkv[(size_t)(b * S + k0n + sr0) * 2304 + 768 + h * 64 + sd0];
      pfK1 = *(const s16x8*)&qkv[(size_t)(b * S + k0n + sr1) * 2304 + 768 + h * 64 + sd0];
      pfV0 = *(const s16x8*)&vt[((size_t)bh * 64 + sr0) * S + k0n + sd0];
      pfV1 = *(const s16x8*)&vt[((size_t)bh * 64 + sr1) * S + k0n + sd0];
      int lo1 = q0 - k0n + 449, lo2 = k0n - q0 + 449;
#pragma unroll
      for (int i = 0; i < 4; i++) {
        int tt = sr0 + i * 32;
        int r1 = lo1 + tt; r1 = r1 < 0 ? 0 : (r1 > M2 - 1 ? M2 - 1 : r1);
        int r2 = lo2 + tt; r2 = r2 < 0 ? 0 : (r2 > M2 - 1 ? M2 - 1 : r2);
        pfPK[i] = *(const s16x8*)&pkq[(size_t)r1 * 1536 + h * 64 + sd0];
        pfPQ[i] = *(const s16x8*)&pkq[(size_t)r2 * 1536 + 768 + h * 64 + sd0];
      }
      if (t < 64) pfTok = tok[b * S + k0n + t];
    }

    // ---- MFMA phase: K-frags (shared c2c-B / pc-A), band B-frags ----
    s16x8 kf[4][2];
#pragma unroll
    for (int m = 0; m < 4; m++)
#pragma unroll
      for (int ks = 0; ks < 2; ks++)
        kf[m][ks] = *(const s16x8*)&KPs[(m * 16 + l15) * RS + ks * 32 + l4 * 8];

    f32x4 c2c[4] = {};
    f32x4 cp[4][2] = {}, pc[4][2] = {};
    __builtin_amdgcn_s_setprio(1);
#pragma unroll
    for (int ks = 0; ks < 2; ks++) {
#pragma unroll
      for (int n = 0; n < 4; n++)
        c2c[n] = __builtin_amdgcn_mfma_f32_16x16x32_bf16(qf[wave][ks], kf[n][ks],
                                                         c2c[n], 0, 0, 0);
#pragma unroll
      for (int u = 0; u < 2; u++) {
        s16x8 bpk = *(const s16x8*)&PKb[(wave * 32 + u * 16 + l15) * RS + ks * 32 + l4 * 8];
        s16x8 bpq = *(const s16x8*)&PQb[(wave * 32 + u * 16 + l15) * RS + ks * 32 + l4 * 8];
#pragma unroll
        for (int m = 0; m < 4; m++) {
          cp[m][u] = __builtin_amdgcn_mfma_f32_16x16x32_bf16(qf[m][ks], bpk,
                                                             cp[m][u], 0, 0, 0);
          pc[m][u] = __builtin_amdgcn_mfma_f32_16x16x32_bf16(kf[m][ks], bpq,
                                                             pc[m][u], 0, 0, 0);
        }
      }
    }
    __builtin_amdgcn_s_setprio(0);
    __syncthreads();                       // [A] band/K LDS reads complete

    // ---- band results -> LDS (wave owns t-cols [wave*32, wave*32+32)) ----
    {
      int rw = l4 << 2;
#pragma unroll
      for (int m = 0; m < 4; m++)
#pragma unroll
        for (int u = 0; u < 2; u++)
#pragma unroll
          for (int j = 0; j < 4; j++) {
            c2pL[(m * 16 + rw + j) * TS + wave * 32 + u * 16 + l15] = f2bf(cp[m][u][j]);
            p2cL[(m * 16 + rw + j) * TS + wave * 32 + u * 16 + l15] = f2bf(pc[m][u][j]);
          }
    }
    __syncthreads();                       // [B] bands visible

    // ---- gather + mask + online softmax (wave's 16 q-rows) ----
    float p[4][4];
    float rmax[4];
#pragma unroll
    for (int j = 0; j < 4; j++) rmax[j] = -1e30f;
#pragma unroll
    for (int n = 0; n < 4; n++) {
      int ik = n * 16 + l15;
      bool msk = (smTok[ik] == 0);
#pragma unroll
      for (int j = 0; j < 4; j++) {
        int iq = wave * 16 + (l4 << 2) + j;
        float sc = c2c[n][j]
                 + bf2f(c2pL[iq * TS + (iq - ik + 63)])
                 + bf2f(p2cL[ik * TS + (ik - iq + 63)]);
        sc *= scale;
        if (msk) sc = -1e9f;
        p[n][j] = sc;
        rmax[j] = fmaxf(rmax[j], sc);
      }
    }
#pragma unroll
    for (int o = 8; o > 0; o >>= 1)
#pragma unroll
      for (int j = 0; j < 4; j++)
        rmax[j] = fmaxf(rmax[j], __shfl_xor(rmax[j], o, 64));
    float al[4];
#pragma unroll
    for (int j = 0; j < 4; j++) {
      float mn = fmaxf(mrow[j], rmax[j]);
      al[j] = __expf(mrow[j] - mn);
      mrow[j] = mn;
    }
    float rs[4] = {0.f, 0.f, 0.f, 0.f};
#pragma unroll
    for (int n = 0; n < 4; n++)
#pragma unroll
      for (int j = 0; j < 4; j++) {
        p[n][j] = __expf(p[n][j] - mrow[j]);
        rs[j] += p[n][j];
      }
#pragma unroll
    for (int o = 8; o > 0; o >>= 1)
#pragma unroll
      for (int j = 0; j < 4; j++) rs[j] += __shfl_xor(rs[j], o, 64);
#pragma unroll
    for (int j = 0; j < 4; j++) lrow[j] = lrow[j] * al[j] + rs[j];
#pragma unroll
    for (int n = 0; n < 4; n++)
#pragma unroll
      for (int j = 0; j < 4; j++) accO[n][j] *= al[j];

    // ---- P -> LDS (alias over KPs; K-frag reads finished at [A]) ----
    {
      int rw = wave * 16 + (l4 << 2);
#pragma unroll
      for (int n = 0; n < 4; n++)
#pragma unroll
        for (int j = 0; j < 4; j++)
          KPs[(rw + j) * RS + n * 16 + l15] = f2bf(p[n][j]);
    }
    __syncthreads();                       // [C] P visible

    // ---- PV: accO += P @ V^T ----
    __builtin_amdgcn_s_setprio(1);
#pragma unroll
    for (int ks = 0; ks < 2; ks++) {
      int koff = ks * 32 + l4 * 8;
      s16x8 ap = *(const s16x8*)&KPs[(wave * 16 + l15) * RS + koff];
#pragma unroll
      for (int n = 0; n < 4; n++) {
        s16x8 bv2 = *(const s16x8*)&Vs[(n * 16 + l15) * RS + koff];
        accO[n] = __builtin_amdgcn_mfma_f32_16x16x32_bf16(ap, bv2, accO[n], 0, 0, 0);
      }
    }
    __builtin_amdgcn_s_setprio(0);
    __syncthreads();                       // [D] all LDS reads of tile done

    // ---- write prefetched tile t+1 into LDS ----
    if (pfv) {
      *(s16x8*)&KPs[sr0 * RS + sd0] = pfK0;
      *(s16x8*)&KPs[sr1 * RS + sd0] = pfK1;
      *(s16x8*)&Vs[sr0 * RS + sd0] = pfV0;
      *(s16x8*)&Vs[sr1 * RS + sd0] = pfV1;
#pragma unroll
      for (int i = 0; i < 4; i++) {
        int tt = sr0 + i * 32;
        *(s16x8*)&PKb[tt * RS + sd0] = pfPK[i];
        *(s16x8*)&PQb[tt * RS + sd0] = pfPQ[i];
      }
      if (t < 64) smTok[t] = pfTok;
    }
    __syncthreads();                       // [E] staged visible
  }

  // ---- epilogue: O = accO / l ----
#pragma unroll
  for (int n = 0; n < 4; n++) {
    int dd = h * 64 + n * 16 + l15;
#pragma unroll
    for (int j = 0; j < 4; j++) {
      int iq = q0 + wave * 16 + (l4 << 2) + j;
      ctx[(size_t)(b * S + iq) * HID + dd] = f2bf(accO[n][j] / lrow[j]);
    }
  }
}

// ---------------------------------------------------------------------------
extern "C" void kernel_launch(void* const* d_in, const int* in_sizes, int n_in,
                              void* d_out, int out_size, void* d_ws,
                              size_t ws_size, hipStream_t stream) {
  (void)in_sizes; (void)n_in; (void)out_size; (void)ws_size;
  const int*   tok     = (const int*)d_in[0];
  const int*   seg     = (const int*)d_in[1];
  const float* tok_emb = (const float*)d_in[2];
  const float* seg_emb = (const float*)d_in[3];
  const float* Wq  = (const float*)d_in[4];
  const float* bq  = (const float*)d_in[5];
  const float* Wk  = (const float*)d_in[6];
  const float* bk  = (const float*)d_in[7];
  const float* Wv  = (const float*)d_in[8];
  const float* bv  = (const float*)d_in[9];
  const float* Wo  = (const float*)d_in[10];
  const float* bo  = (const float*)d_in[11];
  const float* Wpk = (const float*)d_in[12];
  const float* Wpq = (const float*)d_in[13];
  const float* rel = (const float*)d_in[14];
  const float* ln1g = (const float*)d_in[15];
  const float* ln1b = (const float*)d_in[16];
  const float* ln2g = (const float*)d_in[17];
  const float* ln2b = (const float*)d_in[18];
  const float* W1  = (const float*)d_in[19];
  const float* b1  = (const float*)d_in[20];
  const float* W2  = (const float*)d_in[21];
  const float* b2  = (const float*)d_in[22];
  const float* lnfg = (const float*)d_in[23];
  const float* lnfb = (const float*)d_in[24];
  float* out = (float*)d_out;

  // ---- workspace layout ----
  char* base = (char*)d_ws;
  size_t off = 0;
  auto alloc = [&](size_t bytes) -> void* {
    void* p = base + off;
    off += (bytes + 255) & ~(size_t)255;
    return p;
  };
  const size_t XSZ = (size_t)NTOK * HID;
  float* x = (float*)alloc(XSZ * 4);
  unsigned short* qkv16 = (unsigned short*)alloc((size_t)NTOK * 2304 * 2);
  unsigned short* pkq16 = (unsigned short*)alloc((size_t)M2 * 1536 * 2);
  unsigned short* vt16  = (unsigned short*)alloc(XSZ * 2);
  unsigned short* act16 = (unsigned short*)alloc(XSZ * 2);
  unsigned short* ff16  = (unsigned short*)alloc((size_t)NTOK * FF * 2);
  unsigned short* rel16 = (unsigned short*)alloc((size_t)M2 * HID * 2);
  unsigned short* wt6   = (unsigned short*)alloc((size_t)6 * HID * HID * 2);
  unsigned short* wt1   = (unsigned short*)alloc((size_t)HID * FF * 2);
  unsigned short* wt2   = (unsigned short*)alloc((size_t)HID * FF * 2);
  float* skbuf = (float*)alloc((size_t)2 * NTOK * HID * 4);
  float* bqkv  = (float*)alloc((size_t)L * 2304 * 4);

  const size_t WSQ = (size_t)HID * HID;

  embed_kernel<<<NTOK, 256, 0, stream>>>(tok, seg, tok_emb, seg_emb, x);
  concat_bias<<<(L * 2304 + 255) / 256, 256, 0, stream>>>(bq, bk, bv, bqkv);
  ln_kernel<1><<<NTOK / 4, 256, 0, stream>>>(x, act16, ln1g, ln1b, NTOK);

  for (int l = 0; l < L; l++) {
    // ---- weight prep (slots: 0=q 1=k 2=v 3=o 4=pk 5=pq) ----
    transpose6_kernel<<<dim3(HID / 32, HID / 32, 6), 256, 0, stream>>>(
        Wq + l * WSQ, Wk + l * WSQ, Wv + l * WSQ, Wo + l * WSQ,
        Wpk + l * WSQ, Wpq + l * WSQ, wt6);
    transpose_ff<<<dim3(FF / 32, HID / 32, 2), 256, 0, stream>>>(
        W1 + (size_t)l * HID * FF, W2 + (size_t)l * FF * HID, wt1, wt2);
    conv_bf16_kernel<<<(M2 * HID + 255) / 256, 256, 0, stream>>>(
        rel + (size_t)l * M2 * HID, rel16, M2 * HID);

    // ---- attention ----
    mfma_gemm<128, 1, 0, 0><<<dim3(2304 / 128, NTOK / 128, 1), 256, 0, stream>>>(
        act16, wt6, bqkv + l * 2304, nullptr, qkv16, NTOK, HID, 2304, HID);
    mfma_gemm<64, 1, 0, 0><<<dim3(1536 / 64, M2 / 128, 1), 256, 0, stream>>>(
        rel16, wt6 + 4 * WSQ, nullptr, nullptr, pkq16, M2, HID, 1536, HID);
    transpose_v<<<dim3(S / 32, D / 32, B * NH), 256, 0, stream>>>(qkv16, vt16);
    flash_attn<<<dim3(S / 64, B * NH), 256, 0, stream>>>(
        qkv16, pkq16, vt16, tok, act16);
    mfma_gemm<64, 0, 0, 0><<<dim3(HID / 64, NTOK / 128, 1), 256, 0, stream>>>(
        act16, wt6 + 3 * WSQ, bo + l * HID, x, x, NTOK, HID, HID, HID);

    // ---- feedforward ----
    ln_kernel<1><<<NTOK / 4, 256, 0, stream>>>(x, act16, ln2g + l * HID,
                                               ln2b + l * HID, NTOK);
    mfma_gemm<128, 1, 1, 0><<<dim3(FF / 128, NTOK / 128, 1), 256, 0, stream>>>(
        act16, wt1, b1 + l * FF, nullptr, ff16, NTOK, HID, FF, HID);
    mfma_gemm<64, 0, 0, 1><<<dim3(HID / 64, NTOK / 128, 2), 256, 0, stream>>>(
        ff16, wt2, nullptr, nullptr, skbuf, NTOK, FF, HID, FF / 2);
    if (l < L - 1) {
      combine_ln<0><<<NTOK, 256, 0, stream>>>(
          skbuf, x, b2 + l * HID, ln1g + (l + 1) * HID, ln1b + (l + 1) * HID,
          act16);
    } else {
      combine_ln<1><<<NTOK, 256, 0, stream>>>(
          skbuf, x, b2 + l * HID, lnfg, lnfb, out);
    }
  }
}

// Round 6
// 4020.729 us; speedup vs baseline: 1.0069x; 1.0069x over previous
//
#include <hip/hip_runtime.h>
#include <hip/hip_bf16.h>
#include <cstddef>
#include <cstdint>

// ---------------------------------------------------------------------------
// DeBERTa forward, MI355X. Round 6: round-4 flash_attn body + 2-way K-split
// (flash-decoding) with exact combine. GEMM stack unchanged.
// B=8 S=512 HID=768 L=12 NH=12 D=64 FF=3072 2M=1024
// ---------------------------------------------------------------------------

constexpr int B   = 8;
constexpr int S   = 512;
constexpr int HID = 768;
constexpr int L   = 12;
constexpr int NH  = 12;
constexpr int D   = 64;
constexpr int FF  = 3072;
constexpr int M2  = 1024;          // 2*M
constexpr int NTOK = B * S;        // 4096

using f32x4 = __attribute__((ext_vector_type(4))) float;
using s16x8 = __attribute__((ext_vector_type(8))) short;

__device__ inline float wave_sum(float v) {
#pragma unroll
  for (int o = 32; o > 0; o >>= 1) v += __shfl_xor(v, o, 64);
  return v;
}
__device__ inline unsigned short f2bf(float f) {
  __hip_bfloat16 h = __float2bfloat16(f);
  return *reinterpret_cast<unsigned short*>(&h);
}
__device__ inline float bf2f(unsigned short u) {
  union { unsigned int i; float f; } x;
  x.i = ((unsigned int)u) << 16;
  return x.f;
}
#define GLOAD16(gp, lp)                                                  \
  __builtin_amdgcn_global_load_lds(                                     \
      (const __attribute__((address_space(1))) void*)(gp),              \
      (__attribute__((address_space(3))) void*)(lp), 16, 0, 0)

// ---- embeddings -------------------------------------------------------------
__global__ void embed_kernel(const int* __restrict__ tok,
                             const int* __restrict__ seg,
                             const float* __restrict__ tok_emb,
                             const float* __restrict__ seg_emb,
                             float* __restrict__ x) {
  int row = blockIdx.x;
  int s = row & (S - 1);
  int t = tok[row];
  int sg = seg[row];
  for (int c = threadIdx.x; c < HID; c += blockDim.x) {
    int i = c >> 1;
    float ang = (float)s * powf(10000.0f, -2.0f * (float)i / (float)HID);
    float pe = (c & 1) ? cosf(ang) : sinf(ang);
    x[(size_t)row * HID + c] = tok_emb[(size_t)t * HID + c] + pe
                             + seg_emb[(size_t)sg * HID + c];
  }
}

// ---- layernorm (one wave per row) -------------------------------------------
template <int BF16OUT>
__global__ __launch_bounds__(256)
void ln_kernel(const float* __restrict__ in, void* __restrict__ outp,
               const float* __restrict__ g, const float* __restrict__ b,
               int nrows) {
  int wave = threadIdx.x >> 6, lane = threadIdx.x & 63;
  int row = blockIdx.x * 4 + wave;
  if (row >= nrows) return;
  const float* xr = in + (size_t)row * HID;
  float v[12];
  float s = 0.f;
#pragma unroll
  for (int i = 0; i < 12; i++) { v[i] = xr[lane + i * 64]; s += v[i]; }
  s = wave_sum(s);
  float mu = s * (1.0f / HID);
  float ss = 0.f;
#pragma unroll
  for (int i = 0; i < 12; i++) { float d = v[i] - mu; ss += d * d; }
  ss = wave_sum(ss);
  float inv = rsqrtf(ss * (1.0f / HID) + 1e-5f);
#pragma unroll
  for (int i = 0; i < 12; i++) {
    int c = lane + i * 64;
    float o = (v[i] - mu) * inv * g[c] + b[c];
    if (BF16OUT)
      ((unsigned short*)outp)[(size_t)row * HID + c] = f2bf(o);
    else
      ((float*)outp)[(size_t)row * HID + c] = o;
  }
}

// ---- 6 square [HID,HID] weights transpose+bf16 in one dispatch ---------------
__global__ __launch_bounds__(256)
void transpose6_kernel(const float* s0, const float* s1, const float* s2,
                       const float* s3, const float* s4, const float* s5,
                       unsigned short* __restrict__ dst) {
  const float* srcs[6] = {s0, s1, s2, s3, s4, s5};
  const float* src = srcs[blockIdx.z];
  unsigned short* d = dst + (size_t)blockIdx.z * HID * HID;
  __shared__ float tile[32][33];
  int nt = blockIdx.x * 32, kt = blockIdx.y * 32;
  int tx = threadIdx.x & 31, ty = threadIdx.x >> 5;
#pragma unroll
  for (int i = 0; i < 4; i++)
    tile[ty + i * 8][tx] = src[(size_t)(kt + ty + i * 8) * HID + nt + tx];
  __syncthreads();
#pragma unroll
  for (int i = 0; i < 4; i++)
    d[(size_t)(nt + ty + i * 8) * HID + kt + tx] = f2bf(tile[tx][ty + i * 8]);
}

// ---- W1+W2 transpose+bf16 in one dispatch (z=0:W1, z=1:W2) -------------------
__global__ __launch_bounds__(256)
void transpose_ff(const float* __restrict__ W1s, const float* __restrict__ W2s,
                  unsigned short* __restrict__ d1, unsigned short* __restrict__ d2) {
  const float* src = blockIdx.z ? W2s : W1s;
  unsigned short* dst = blockIdx.z ? d2 : d1;
  int K = blockIdx.z ? FF : HID;   // src rows
  int N = blockIdx.z ? HID : FF;   // src cols
  int nt, kt;
  if (blockIdx.z) { nt = blockIdx.y * 32; kt = blockIdx.x * 32; }
  else            { nt = blockIdx.x * 32; kt = blockIdx.y * 32; }
  __shared__ float tile[32][33];
  int tx = threadIdx.x & 31, ty = threadIdx.x >> 5;
#pragma unroll
  for (int i = 0; i < 4; i++)
    tile[ty + i * 8][tx] = src[(size_t)(kt + ty + i * 8) * N + nt + tx];
  __syncthreads();
#pragma unroll
  for (int i = 0; i < 4; i++)
    dst[(size_t)(nt + ty + i * 8) * K + kt + tx] = f2bf(tile[tx][ty + i * 8]);
}

__global__ void conv_bf16_kernel(const float* __restrict__ src,
                                 unsigned short* __restrict__ dst, int n) {
  int i = blockIdx.x * 256 + threadIdx.x;
  if (i < n) dst[i] = f2bf(src[i]);
}

__global__ void concat_bias(const float* __restrict__ bq,
                            const float* __restrict__ bk,
                            const float* __restrict__ bv,
                            float* __restrict__ bqkv) {
  int i = blockIdx.x * 256 + threadIdx.x;
  if (i >= L * 2304) return;
  int l = i / 2304, c = i % 2304;
  float v = (c < 768) ? bq[l * 768 + c]
          : (c < 1536) ? bk[l * 768 + c - 768] : bv[l * 768 + c - 1536];
  bqkv[i] = v;
}

// ---- bf16 MFMA GEMM, 128xTN tile, optional split-K partial ------------------
template <int TN, int OUT_BF16, int GELU, int PARTIAL>
__global__ __launch_bounds__(256)
void mfma_gemm(const unsigned short* __restrict__ A,
               const unsigned short* __restrict__ Bt,
               const float* __restrict__ bias, const float* __restrict__ res,
               void* __restrict__ C, int Mr, int K, int N, int Kc) {
  constexpr int NW = TN / 32;
  __shared__ unsigned short As[128 * 32];
  __shared__ unsigned short Bs[TN * 32];
  int t = threadIdx.x, wave = t >> 6, lane = t & 63;
  int r0 = blockIdx.y * 128, n0 = blockIdx.x * TN;
  int kb = blockIdx.z * Kc;
  int wr = (wave >> 1) * 64;
  int wc = (wave & 1) * (TN / 2);

  f32x4 acc[4][NW] = {};
  int srow = lane >> 2, selem = (lane & 3) * 8;

  for (int k0 = kb; k0 < kb + Kc; k0 += 32) {
    __syncthreads();
    {
      const unsigned short* gA =
          A + (size_t)(r0 + wave * 32 + srow) * K + k0 + selem;
      unsigned short* lA = &As[(wave * 32) * 32];
      GLOAD16(gA, lA);
      GLOAD16(gA + (size_t)16 * K, lA + 16 * 32);
      if (TN == 128) {
        const unsigned short* gB =
            Bt + (size_t)(n0 + wave * 32 + srow) * K + k0 + selem;
        unsigned short* lB = &Bs[(wave * 32) * 32];
        GLOAD16(gB, lB);
        GLOAD16(gB + (size_t)16 * K, lB + 16 * 32);
      } else {
        const unsigned short* gB =
            Bt + (size_t)(n0 + wave * 16 + srow) * K + k0 + selem;
        GLOAD16(gB, &Bs[(wave * 16) * 32]);
      }
    }
    __syncthreads();

    s16x8 af[4], bf[NW];
#pragma unroll
    for (int m = 0; m < 4; m++)
      af[m] = *(const s16x8*)&As[(wr + m * 16 + (lane & 15)) * 32 + (lane >> 4) * 8];
#pragma unroll
    for (int n = 0; n < NW; n++)
      bf[n] = *(const s16x8*)&Bs[(wc + n * 16 + (lane & 15)) * 32 + (lane >> 4) * 8];
#pragma unroll
    for (int m = 0; m < 4; m++)
#pragma unroll
      for (int n = 0; n < NW; n++)
        acc[m][n] = __builtin_amdgcn_mfma_f32_16x16x32_bf16(af[m], bf[n],
                                                            acc[m][n], 0, 0, 0);
  }

  if (PARTIAL) {
    float* Cp = (float*)C + (size_t)blockIdx.z * Mr * N;
#pragma unroll
    for (int n = 0; n < NW; n++) {
      int c = n0 + wc + n * 16 + (lane & 15);
#pragma unroll
      for (int m = 0; m < 4; m++) {
        int rb = r0 + wr + m * 16 + ((lane >> 4) << 2);
#pragma unroll
        for (int j = 0; j < 4; j++)
          Cp[(size_t)(rb + j) * N + c] = acc[m][n][j];
      }
    }
    return;
  }
#pragma unroll
  for (int n = 0; n < NW; n++) {
    int c = n0 + wc + n * 16 + (lane & 15);
    float bv = bias ? bias[c] : 0.f;
#pragma unroll
    for (int m = 0; m < 4; m++) {
      int rb = r0 + wr + m * 16 + ((lane >> 4) << 2);
#pragma unroll
      for (int j = 0; j < 4; j++) {
        int r = rb + j;
        float val = acc[m][n][j] + bv;
        if (GELU) val = 0.5f * val * (1.0f + erff(val * 0.70710678118654752f));
        if (res)  val += res[(size_t)r * N + c];
        if (OUT_BF16)
          ((unsigned short*)C)[(size_t)r * N + c] = f2bf(val);
        else
          ((float*)C)[(size_t)r * N + c] = val;
      }
    }
  }
}

// ---- split-K combine + residual + LN ----------------------------------------
template <int LAST>
__global__ __launch_bounds__(256)
void combine_ln(const float* __restrict__ part,   // [2][NTOK][HID]
                float* __restrict__ x, const float* __restrict__ bias,
                const float* __restrict__ g, const float* __restrict__ bb,
                void* __restrict__ outp) {
  int row = blockIdx.x, t = threadIdx.x;
  int wave = t >> 6, lane = t & 63;
  __shared__ float red[4];
  float v[3];
  float s = 0.f;
#pragma unroll
  for (int i = 0; i < 3; i++) {
    int c = t + i * 256;
    size_t idx = (size_t)row * HID + c;
    float val = x[idx] + part[idx] + part[(size_t)NTOK * HID + idx] + bias[c];
    if (!LAST) x[idx] = val;
    v[i] = val;
    s += val;
  }
  s = wave_sum(s);
  if (lane == 0) red[wave] = s;
  __syncthreads();
  float mu = (red[0] + red[1] + red[2] + red[3]) * (1.0f / HID);
  float ss = 0.f;
#pragma unroll
  for (int i = 0; i < 3; i++) { float d = v[i] - mu; ss += d * d; }
  ss = wave_sum(ss);
  __syncthreads();
  if (lane == 0) red[wave] = ss;
  __syncthreads();
  float inv = rsqrtf((red[0] + red[1] + red[2] + red[3]) * (1.0f / HID) + 1e-5f);
#pragma unroll
  for (int i = 0; i < 3; i++) {
    int c = t + i * 256;
    float o = (v[i] - mu) * inv * g[c] + bb[c];
    if (LAST)
      ((float*)outp)[(size_t)row * HID + c] = o;
    else
      ((unsigned short*)outp)[(size_t)row * HID + c] = f2bf(o);
  }
}

// ---- V transpose from fused qkv ----------------------------------------------
__global__ __launch_bounds__(256)
void transpose_v(const unsigned short* __restrict__ qkv,
                 unsigned short* __restrict__ vt) {
  __shared__ unsigned short tile[32][34];
  int bh = blockIdx.z;
  int b = bh / NH, h = bh % NH;
  int s0 = blockIdx.x * 32, d0 = blockIdx.y * 32;
  int tx = threadIdx.x & 31, ty = threadIdx.x >> 5;
#pragma unroll
  for (int i = 0; i < 4; i++)
    tile[ty + i * 8][tx] =
        qkv[(size_t)(b * S + s0 + ty + i * 8) * 2304 + 1536 + h * 64 + d0 + tx];
  __syncthreads();
#pragma unroll
  for (int i = 0; i < 4; i++)
    vt[((size_t)bh * 64 + d0 + ty + i * 8) * S + s0 + tx] = tile[tx][ty + i * 8];
}

// ---- flash attention (round-4 body) with 2-way K-split ----------------------
// grid (S/64, B*NH, 2): block handles q-tile x 4 k-tiles (z picks half).
// Writes unnormalized O partial + per-row (m,l) for exact combine.
__global__ __launch_bounds__(256)
void flash_attn(const unsigned short* __restrict__ qkv,
                const unsigned short* __restrict__ pkq,  // [1024][1536] pk|pq
                const unsigned short* __restrict__ vt,   // [B*NH*64][S]
                const int* __restrict__ tok,
                float* __restrict__ pO,    // [768][2][64][64]
                float* __restrict__ pML) { // [768][2][2][64]
  constexpr int RS = 72, TS = 130;
  __shared__ unsigned short Qs[64 * RS];
  __shared__ unsigned short KPs[64 * RS];       // K tile; aliased to P
  __shared__ unsigned short Vs[64 * RS];        // V^T tile [d][k]
  __shared__ unsigned short Band[2 * 128 * RS]; // PKb|PQb; aliased c2pL|p2cL
  __shared__ int smTok[64];
  unsigned short* PKb = Band;
  unsigned short* PQb = Band + 128 * RS;
  unsigned short* c2pL = Band;                  // [64][TS]
  unsigned short* p2cL = Band + 64 * TS;        // [64][TS]

  int t = threadIdx.x, wave = t >> 6, lane = t & 63;
  int bh = blockIdx.y;
  int b = bh / NH, h = bh % NH;
  int q0 = blockIdx.x * 64;
  int kr0 = blockIdx.z * 256;
  int l15 = lane & 15, l4 = lane >> 4;

#pragma unroll
  for (int i = 0; i < 2; i++) {
    int c = t + i * 256;
    int r = c >> 3, d0 = (c & 7) * 8;
    *(s16x8*)&Qs[r * RS + d0] =
        *(const s16x8*)&qkv[(size_t)(b * S + q0 + r) * 2304 + h * 64 + d0];
  }

  float m[4], l[4];
  f32x4 accO[4];
#pragma unroll
  for (int j = 0; j < 4; j++) { m[j] = -1e30f; l[j] = 0.f; }
#pragma unroll
  for (int n = 0; n < 4; n++) accO[n] = (f32x4){0.f, 0.f, 0.f, 0.f};

  const float scale = 0.07216878364870323f;   // 1/sqrt(3*64)

  for (int k0 = kr0; k0 < kr0 + 256; k0 += 64) {
    // ---- stage K, V^T, bands, tok mask ----
#pragma unroll
    for (int i = 0; i < 2; i++) {
      int c = t + i * 256;
      int r = c >> 3, d0 = (c & 7) * 8;
      *(s16x8*)&KPs[r * RS + d0] =
          *(const s16x8*)&qkv[(size_t)(b * S + k0 + r) * 2304 + 768 + h * 64 + d0];
      *(s16x8*)&Vs[r * RS + d0] =
          *(const s16x8*)&vt[((size_t)bh * 64 + r) * S + k0 + d0];
    }
    int lo1 = q0 - k0 + 449;
    int lo2 = k0 - q0 + 449;
#pragma unroll
    for (int i = 0; i < 4; i++) {
      int c = t + i * 256;
      int tt = c >> 3, d0 = (c & 7) * 8;
      int r1 = lo1 + tt; r1 = r1 < 0 ? 0 : (r1 > M2 - 1 ? M2 - 1 : r1);
      int r2 = lo2 + tt; r2 = r2 < 0 ? 0 : (r2 > M2 - 1 ? M2 - 1 : r2);
      *(s16x8*)&PKb[tt * RS + d0] =
          *(const s16x8*)&pkq[(size_t)r1 * 1536 + h * 64 + d0];
      *(s16x8*)&PQb[tt * RS + d0] =
          *(const s16x8*)&pkq[(size_t)r2 * 1536 + 768 + h * 64 + d0];
    }
    if (t < 64) smTok[t] = tok[b * S + k0 + t];
    __syncthreads();                                  // (1) staging visible

    // ---- MFMAs: c2c (QK^T), cp (Q.pk band), pc (K.pq band) ----
    f32x4 c2c[4] = {};
    f32x4 cp[8] = {}, pc[8] = {};
#pragma unroll
    for (int ks = 0; ks < 2; ks++) {
      int koff = ks * 32 + l4 * 8;
      s16x8 aq = *(const s16x8*)&Qs[(wave * 16 + l15) * RS + koff];
      s16x8 ak = *(const s16x8*)&KPs[(wave * 16 + l15) * RS + koff];
#pragma unroll
      for (int n = 0; n < 4; n++) {
        s16x8 bk = *(const s16x8*)&KPs[(n * 16 + l15) * RS + koff];
        c2c[n] = __builtin_amdgcn_mfma_f32_16x16x32_bf16(aq, bk, c2c[n], 0, 0, 0);
      }
#pragma unroll
      for (int tt = 0; tt < 8; tt++) {
        s16x8 bpk = *(const s16x8*)&PKb[(tt * 16 + l15) * RS + koff];
        s16x8 bpq = *(const s16x8*)&PQb[(tt * 16 + l15) * RS + koff];
        cp[tt] = __builtin_amdgcn_mfma_f32_16x16x32_bf16(aq, bpk, cp[tt], 0, 0, 0);
        pc[tt] = __builtin_amdgcn_mfma_f32_16x16x32_bf16(ak, bpq, pc[tt], 0, 0, 0);
      }
    }
    __syncthreads();                                  // (2) band reads done

    {
      int rw = wave * 16 + (l4 << 2);
#pragma unroll
      for (int tt = 0; tt < 8; tt++)
#pragma unroll
        for (int j = 0; j < 4; j++) {
          c2pL[(rw + j) * TS + tt * 16 + l15] = f2bf(cp[tt][j]);
          p2cL[(rw + j) * TS + tt * 16 + l15] = f2bf(pc[tt][j]);
        }
    }
    __syncthreads();                                  // (3) bands visible

    // ---- gather + mask + online softmax (wave's 16 q-rows) ----
    float p[4][4];
    float rmax[4];
#pragma unroll
    for (int j = 0; j < 4; j++) rmax[j] = -1e30f;
#pragma unroll
    for (int n = 0; n < 4; n++) {
      int ik = n * 16 + l15;
      bool msk = (smTok[ik] == 0);
#pragma unroll
      for (int j = 0; j < 4; j++) {
        int iq = wave * 16 + (l4 << 2) + j;
        float sc = c2c[n][j]
                 + bf2f(c2pL[iq * TS + (iq - ik + 63)])
                 + bf2f(p2cL[ik * TS + (ik - iq + 63)]);
        sc *= scale;
        if (msk) sc = -1e9f;
        p[n][j] = sc;
        rmax[j] = fmaxf(rmax[j], sc);
      }
    }
#pragma unroll
    for (int o = 8; o > 0; o >>= 1)
#pragma unroll
      for (int j = 0; j < 4; j++)
        rmax[j] = fmaxf(rmax[j], __shfl_xor(rmax[j], o, 64));
    float al[4];
#pragma unroll
    for (int j = 0; j < 4; j++) {
      float mn = fmaxf(m[j], rmax[j]);
      al[j] = __expf(m[j] - mn);
      m[j] = mn;
    }
    float rs[4] = {0.f, 0.f, 0.f, 0.f};
#pragma unroll
    for (int n = 0; n < 4; n++)
#pragma unroll
      for (int j = 0; j < 4; j++) {
        p[n][j] = __expf(p[n][j] - m[j]);
        rs[j] += p[n][j];
      }
#pragma unroll
    for (int o = 8; o > 0; o >>= 1)
#pragma unroll
      for (int j = 0; j < 4; j++) rs[j] += __shfl_xor(rs[j], o, 64);
#pragma unroll
    for (int j = 0; j < 4; j++) l[j] = l[j] * al[j] + rs[j];
#pragma unroll
    for (int n = 0; n < 4; n++)
#pragma unroll
      for (int j = 0; j < 4; j++) accO[n][j] *= al[j];

    // ---- P -> LDS (alias over KPs) in [q][k] layout ----
    {
      int rw = wave * 16 + (l4 << 2);
#pragma unroll
      for (int n = 0; n < 4; n++)
#pragma unroll
        for (int j = 0; j < 4; j++)
          KPs[(rw + j) * RS + n * 16 + l15] = f2bf(p[n][j]);
    }
    __syncthreads();                                  // (4) P visible

    // ---- PV: accO += P @ V ----
#pragma unroll
    for (int ks = 0; ks < 2; ks++) {
      int koff = ks * 32 + l4 * 8;
      s16x8 ap = *(const s16x8*)&KPs[(wave * 16 + l15) * RS + koff];
#pragma unroll
      for (int n = 0; n < 4; n++) {
        s16x8 bv2 = *(const s16x8*)&Vs[(n * 16 + l15) * RS + koff];
        accO[n] = __builtin_amdgcn_mfma_f32_16x16x32_bf16(ap, bv2, accO[n], 0, 0, 0);
      }
    }
    __syncthreads();                                  // (5) P/V reads done
  }

  // ---- epilogue: write unnormalized partial O and (m,l) ----
  int pb = bh * 8 + blockIdx.x;
  float* Ob = pO + (((size_t)pb * 2 + blockIdx.z) << 12);
#pragma unroll
  for (int n = 0; n < 4; n++) {
#pragma unroll
    for (int j = 0; j < 4; j++) {
      int row = wave * 16 + (l4 << 2) + j;
      Ob[row * 64 + n * 16 + l15] = accO[n][j];
    }
  }
  if (l15 == 0) {
    float* mlb = pML + ((size_t)pb * 2 + blockIdx.z) * 128;
#pragma unroll
    for (int j = 0; j < 4; j++) {
      int row = wave * 16 + (l4 << 2) + j;
      mlb[row] = m[j];
      mlb[64 + row] = l[j];
    }
  }
}

// ---- combine two K-split halves: exact online-softmax merge -----------------
__global__ __launch_bounds__(256)
void flash_combine(const float* __restrict__ pO, const float* __restrict__ pML,
                   unsigned short* __restrict__ ctx) {
  int pb = blockIdx.x;                 // 0..767
  int bh = pb >> 3, qt = pb & 7;
  int b = bh / NH, h = bh % NH;
  int t = threadIdx.x;
  int r = t >> 2, c0 = (t & 3) * 16;
  const float* ml = pML + (size_t)pb * 256;
  float m1 = ml[r], l1 = ml[64 + r];
  float m2 = ml[128 + r], l2 = ml[192 + r];
  float M = fmaxf(m1, m2);
  float a1 = __expf(m1 - M), a2 = __expf(m2 - M);
  float linv = 1.0f / (a1 * l1 + a2 * l2);
  const float* O1 = pO + ((size_t)pb * 2) * 4096 + r * 64 + c0;
  const float* O2 = O1 + 4096;
  unsigned short* o = ctx + (size_t)(b * S + qt * 64 + r) * HID + h * 64 + c0;
#pragma unroll
  for (int i = 0; i < 4; i++) {
    f32x4 v1 = *(const f32x4*)&O1[i * 4];
    f32x4 v2 = *(const f32x4*)&O2[i * 4];
#pragma unroll
    for (int j = 0; j < 4; j++)
      o[i * 4 + j] = f2bf((a1 * v1[j] + a2 * v2[j]) * linv);
  }
}

// ---------------------------------------------------------------------------
extern "C" void kernel_launch(void* const* d_in, const int* in_sizes, int n_in,
                              void* d_out, int out_size, void* d_ws,
                              size_t ws_size, hipStream_t stream) {
  (void)in_sizes; (void)n_in; (void)out_size; (void)ws_size;
  const int*   tok     = (const int*)d_in[0];
  const int*   seg     = (const int*)d_in[1];
  const float* tok_emb = (const float*)d_in[2];
  const float* seg_emb = (const float*)d_in[3];
  const float* Wq  = (const float*)d_in[4];
  const float* bq  = (const float*)d_in[5];
  const float* Wk  = (const float*)d_in[6];
  const float* bk  = (const float*)d_in[7];
  const float* Wv  = (const float*)d_in[8];
  const float* bv  = (const float*)d_in[9];
  const float* Wo  = (const float*)d_in[10];
  const float* bo  = (const float*)d_in[11];
  const float* Wpk = (const float*)d_in[12];
  const float* Wpq = (const float*)d_in[13];
  const float* rel = (const float*)d_in[14];
  const float* ln1g = (const float*)d_in[15];
  const float* ln1b = (const float*)d_in[16];
  const float* ln2g = (const float*)d_in[17];
  const float* ln2b = (const float*)d_in[18];
  const float* W1  = (const float*)d_in[19];
  const float* b1  = (const float*)d_in[20];
  const float* W2  = (const float*)d_in[21];
  const float* b2  = (const float*)d_in[22];
  const float* lnfg = (const float*)d_in[23];
  const float* lnfb = (const float*)d_in[24];
  float* out = (float*)d_out;

  // ---- workspace layout ----
  char* base = (char*)d_ws;
  size_t off = 0;
  auto alloc = [&](size_t bytes) -> void* {
    void* p = base + off;
    off += (bytes + 255) & ~(size_t)255;
    return p;
  };
  const size_t XSZ = (size_t)NTOK * HID;
  float* x = (float*)alloc(XSZ * 4);
  unsigned short* qkv16 = (unsigned short*)alloc((size_t)NTOK * 2304 * 2);
  unsigned short* pkq16 = (unsigned short*)alloc((size_t)M2 * 1536 * 2);
  unsigned short* vt16  = (unsigned short*)alloc(XSZ * 2);
  unsigned short* act16 = (unsigned short*)alloc(XSZ * 2);
  unsigned short* ff16  = (unsigned short*)alloc((size_t)NTOK * FF * 2);
  unsigned short* rel16 = (unsigned short*)alloc((size_t)M2 * HID * 2);
  unsigned short* wt6   = (unsigned short*)alloc((size_t)6 * HID * HID * 2);
  unsigned short* wt1   = (unsigned short*)alloc((size_t)HID * FF * 2);
  unsigned short* wt2   = (unsigned short*)alloc((size_t)HID * FF * 2);
  float* skbuf = (float*)alloc((size_t)2 * NTOK * HID * 4);
  float* bqkv  = (float*)alloc((size_t)L * 2304 * 4);

  // flash partials alias buffers that are dead during attention:
  //   pO  (25.2 MB) -> skbuf (written by W2 split-K AFTER flash_combine)
  //   pML (0.8 MB)  -> ff16  (written by W1 AFTER flash_combine)
  float* pO  = skbuf;
  float* pML = (float*)ff16;

  const size_t WSQ = (size_t)HID * HID;

  embed_kernel<<<NTOK, 256, 0, stream>>>(tok, seg, tok_emb, seg_emb, x);
  concat_bias<<<(L * 2304 + 255) / 256, 256, 0, stream>>>(bq, bk, bv, bqkv);
  ln_kernel<1><<<NTOK / 4, 256, 0, stream>>>(x, act16, ln1g, ln1b, NTOK);

  for (int l = 0; l < L; l++) {
    // ---- weight prep (slots: 0=q 1=k 2=v 3=o 4=pk 5=pq) ----
    transpose6_kernel<<<dim3(HID / 32, HID / 32, 6), 256, 0, stream>>>(
        Wq + l * WSQ, Wk + l * WSQ, Wv + l * WSQ, Wo + l * WSQ,
        Wpk + l * WSQ, Wpq + l * WSQ, wt6);
    transpose_ff<<<dim3(FF / 32, HID / 32, 2), 256, 0, stream>>>(
        W1 + (size_t)l * HID * FF, W2 + (size_t)l * FF * HID, wt1, wt2);
    conv_bf16_kernel<<<(M2 * HID + 255) / 256, 256, 0, stream>>>(
        rel + (size_t)l * M2 * HID, rel16, M2 * HID);

    // ---- attention ----
    mfma_gemm<128, 1, 0, 0><<<dim3(2304 / 128, NTOK / 128, 1), 256, 0, stream>>>(
        act16, wt6, bqkv + l * 2304, nullptr, qkv16, NTOK, HID, 2304, HID);
    mfma_gemm<64, 1, 0, 0><<<dim3(1536 / 64, M2 / 128, 1), 256, 0, stream>>>(
        rel16, wt6 + 4 * WSQ, nullptr, nullptr, pkq16, M2, HID, 1536, HID);
    transpose_v<<<dim3(S / 32, D / 32, B * NH), 256, 0, stream>>>(qkv16, vt16);
    flash_attn<<<dim3(S / 64, B * NH, 2), 256, 0, stream>>>(
        qkv16, pkq16, vt16, tok, pO, pML);
    flash_combine<<<B * NH * (S / 64), 256, 0, stream>>>(pO, pML, act16);
    mfma_gemm<64, 0, 0, 0><<<dim3(HID / 64, NTOK / 128, 1), 256, 0, stream>>>(
        act16, wt6 + 3 * WSQ, bo + l * HID, x, x, NTOK, HID, HID, HID);

    // ---- feedforward ----
    ln_kernel<1><<<NTOK / 4, 256, 0, stream>>>(x, act16, ln2g + l * HID,
                                               ln2b + l * HID, NTOK);
    mfma_gemm<128, 1, 1, 0><<<dim3(FF / 128, NTOK / 128, 1), 256, 0, stream>>>(
        act16, wt1, b1 + l * FF, nullptr, ff16, NTOK, HID, FF, HID);
    mfma_gemm<64, 0, 0, 1><<<dim3(HID / 64, NTOK / 128, 2), 256, 0, stream>>>(
        ff16, wt2, nullptr, nullptr, skbuf, NTOK, FF, HID, FF / 2);
    if (l < L - 1) {
      combine_ln<0><<<NTOK, 256, 0, stream>>>(
          skbuf, x, b2 + l * HID, ln1g + (l + 1) * HID, ln1b + (l + 1) * HID,
          act16);
    } else {
      combine_ln<1><<<NTOK, 256, 0, stream>>>(
          skbuf, x, b2 + l * HID, lnfg, lnfb, out);
    }
  }
}